// Round 12
// baseline (83.112 us; speedup 1.0000x reference)
//
#include <hip/hip_runtime.h>

typedef unsigned short u16;
typedef unsigned int u32;
typedef __bf16 bf16x8 __attribute__((ext_vector_type(8)));
typedef float f32x4 __attribute__((ext_vector_type(4)));
typedef unsigned short u16x4 __attribute__((ext_vector_type(4)));

#define LOG2E 1.4426950408889634f

#if __has_builtin(__builtin_amdgcn_exp2f)
#define EXP2F(x) __builtin_amdgcn_exp2f(x)
#else
#define EXP2F(x) exp2f(x)
#endif

__device__ __forceinline__ u16 f2bf(float f) {
    union { float f; u32 u; } a; a.f = f;
    u32 u = a.u;
    u += 0x7FFFu + ((u >> 16) & 1u);   // RNE (finite inputs)
    return (u16)(u >> 16);
}
__device__ __forceinline__ bf16x8 ldg8(const u16* p) {
    return *reinterpret_cast<const bf16x8*>(p);
}
#if __has_builtin(__builtin_amdgcn_cvt_pk_bf16_f32)
__device__ __forceinline__ u32 pack2(float a, float b) {
    auto r = __builtin_amdgcn_cvt_pk_bf16_f32(a, b);   // v_cvt_pk_bf16_f32
    return __builtin_bit_cast(u32, r);
}
#else
__device__ __forceinline__ u32 pack2(float a, float b) {
    u32 ua = __float_as_uint(a) + 0x8000u;
    u32 ub = __float_as_uint(b) + 0x8000u;
    return __builtin_amdgcn_perm(ub, ua, 0x07060302);
}
#endif
// async global -> LDS, 16 B per lane. LDS dest = wave-uniform base + lane*16.
__device__ __forceinline__ void async16(const void* g, void* l) {
    __builtin_amdgcn_global_load_lds(
        (const __attribute__((address_space(1))) u32*)g,
        (__attribute__((address_space(3))) u32*)l, 16, 0, 0);
}

#define MFMA16(a, b, c) __builtin_amdgcn_mfma_f32_16x16x32_bf16((a), (b), (c), 0, 0, 0)

// ---------------------------------------------------------------------------
// Fused prep: y<8 -> transpose X tile; y in 8..11 -> pack weight matrix;
// y==12 -> lqw * log2(e) into global fp32 (4 blocks). Grid (64, 13).
// ---------------------------------------------------------------------------
__global__ __launch_bounds__(256) void prep(const float* __restrict__ X,
                                            u16* __restrict__ Xt,
                                            const float* __restrict__ s0,
                                            const float* __restrict__ s1,
                                            const float* __restrict__ s2,
                                            const float* __restrict__ s3,
                                            u16* __restrict__ Wqkv,
                                            u16* __restrict__ Wp,
                                            const float* __restrict__ lqw,
                                            float* __restrict__ lqw2g) {
    __shared__ u16 tile[64][65];
    const int tid = threadIdx.x;
    const int y = blockIdx.y;

    if (y < 8) {                                  // transpose 64x64 tile
        const int t0 = blockIdx.x * 64;
        const int c0 = y * 64;
#pragma unroll
        for (int i = 0; i < 16; ++i) {
            int idx = tid + i * 256;
            int r = idx >> 6, cc = idx & 63;
            tile[r][cc] = f2bf(X[(size_t)(c0 + r) * 4096 + t0 + cc]);
        }
        __syncthreads();
#pragma unroll
        for (int i = 0; i < 16; ++i) {
            int idx = tid + i * 256;
            int tr = idx >> 6, cc = idx & 63;
            Xt[(size_t)(t0 + tr) * 512 + c0 + cc] = tile[cc][tr];
        }
    } else if (y < 12) {                          // pack one 512x512 weight
        const int m = y - 8;
        const float* s = (m == 0) ? s0 : (m == 1) ? s1 : (m == 2) ? s2 : s3;
        u16* d = (m == 3) ? Wp : Wqkv + (size_t)m * 262144;
#pragma unroll
        for (int j = 0; j < 4; ++j) {
            int i = blockIdx.x * 1024 + j * 256 + tid;
            float4 v = reinterpret_cast<const float4*>(s)[i];
            u16x4 o;
            o[0] = f2bf(v.x); o[1] = f2bf(v.y); o[2] = f2bf(v.z); o[3] = f2bf(v.w);
            reinterpret_cast<u16x4*>(d)[i] = o;
        }
    } else {                                      // lqw * LOG2E (1024 float4)
        if (blockIdx.x < 4) {
            int i = blockIdx.x * 256 + tid;
            float4 v = reinterpret_cast<const float4*>(lqw)[i];
            v.x *= LOG2E; v.y *= LOG2E; v.z *= LOG2E; v.w *= LOG2E;
            reinterpret_cast<float4*>(lqw2g)[i] = v;
        }
    }
}

// ---------------------------------------------------------------------------
// Fused QKV GEMM, LDS-staged (R4/R10 version, known-good: Qt/Kt token-major,
// Vp d-major with the proven column permutation).
// ---------------------------------------------------------------------------
__global__ __launch_bounds__(512, 2) void qkv_gemm(const u16* __restrict__ Wqkv,
                                                   const u16* __restrict__ Xt,
                                                   const float* __restrict__ qb,
                                                   const float* __restrict__ kb,
                                                   const float* __restrict__ vb,
                                                   u16* __restrict__ Qt,
                                                   u16* __restrict__ Kt,
                                                   u16* __restrict__ Vp) {
    __shared__ __align__(16) u16 Al[2][128 * 32];
    __shared__ __align__(16) u16 Bl[2][128 * 32];

    const int tid = threadIdx.x;
    const int w = tid >> 6, lane = tid & 63;
    const int quad = lane >> 4, lm = lane & 15;
    const int wm = w & 1, wn = w >> 1;
    const int n0 = blockIdx.x * 128;
    const int my = blockIdx.y;
    const int m0 = my * 128;

    const int arow = lane >> 2;
    const int sch = (lane & 3) ^ ((lane >> 3) & 3);   // source chunk (XOR on row>>1)
    const u16* agp = Wqkv + (size_t)(m0 + w * 16 + arow) * 512 + sch * 8;
    const u16* bgp = Xt + (size_t)(n0 + w * 16 + arow) * 512 + sch * 8;

    async16(agp, &Al[0][w * 16 * 32]);
    async16(bgp, &Bl[0][w * 16 * 32]);
    agp += 32; bgp += 32;

    const int FOFF = lm * 64 + ((quad ^ ((lm >> 1) & 3)) << 4);

    f32x4 acc[4][2];
#pragma unroll
    for (int mt = 0; mt < 4; ++mt)
#pragma unroll
        for (int bt = 0; bt < 2; ++bt) acc[mt][bt] = (f32x4){0.f, 0.f, 0.f, 0.f};

    __syncthreads();

    for (int s = 0; s < 16; ++s) {
        const int buf = s & 1;
        if (s < 15) {
            async16(agp, &Al[buf ^ 1][w * 16 * 32]);
            async16(bgp, &Bl[buf ^ 1][w * 16 * 32]);
            agp += 32; bgp += 32;
        }
        const char* Ab = (const char*)&Al[buf][0];
        const char* Bb = (const char*)&Bl[buf][0];
        bf16x8 af[4], bfr[2];
#pragma unroll
        for (int mt = 0; mt < 4; ++mt)
            af[mt] = *(const bf16x8*)(Ab + wm * 4096 + mt * 1024 + FOFF);
#pragma unroll
        for (int bt = 0; bt < 2; ++bt)
            bfr[bt] = *(const bf16x8*)(Bb + wn * 2048 + bt * 1024 + FOFF);
#pragma unroll
        for (int mt = 0; mt < 4; ++mt)
#pragma unroll
            for (int bt = 0; bt < 2; ++bt)
                acc[mt][bt] = MFMA16(af[mt], bfr[bt], acc[mt][bt]);
        __syncthreads();
    }

    const int mat = my >> 2;                     // 0=Q, 1=K, 2=V
    const float* bias = (mat == 0) ? qb : (mat == 1) ? kb : vb;
    const int chbase = (my & 3) * 128 + wm * 64 + quad * 4;

    if (mat < 2) {
        u16* out = mat ? Kt : Qt;
        const float sc = mat ? 1.0f : 0.125f * LOG2E;
#pragma unroll
        for (int mt = 0; mt < 4; ++mt) {
            const int ch = chbase + mt * 16;
            float4 bv = *(const float4*)(bias + ch);
            float bvf[4] = {bv.x, bv.y, bv.z, bv.w};
#pragma unroll
            for (int bt = 0; bt < 2; ++bt) {
                int tok = n0 + wn * 32 + bt * 16 + lm;
                u16x4 pk;
#pragma unroll
                for (int r = 0; r < 4; ++r)
                    pk[r] = f2bf((acc[mt][bt][r] + bvf[r]) * sc);
                *(u16x4*)(out + (size_t)tok * 512 + ch) = pk;
            }
        }
    } else {
#pragma unroll
        for (int mt = 0; mt < 4; ++mt) {
            const int ch = chbase + mt * 16;
            float4 bv = *(const float4*)(bias + ch);
            float bvf[4] = {bv.x, bv.y, bv.z, bv.w};
#pragma unroll
            for (int bt = 0; bt < 2; ++bt) {
                int g = bt * 16 + lm;
                int col = n0 + wn * 32 + 8 * ((g >> 2) & 3) + 4 * ((g >> 4) & 1) + (g & 3);
#pragma unroll
                for (int r = 0; r < 4; ++r)
                    Vp[(size_t)(ch + r) * 4096 + col] = f2bf(acc[mt][bt][r] + bvf[r]);
            }
        }
    }
}

// ---------------------------------------------------------------------------
// Output projection, LDS-staged (unchanged, known-good).
// ---------------------------------------------------------------------------
__global__ __launch_bounds__(256, 2) void out_gemm(const u16* __restrict__ Wp,
                                                   const u16* __restrict__ Ot,
                                                   const float* __restrict__ pb,
                                                   float* __restrict__ out) {
    __shared__ __align__(16) u16 Al[2][128 * 32];
    __shared__ __align__(16) u16 Bl[2][64 * 32];

    const int tid = threadIdx.x;
    const int w = tid >> 6, lane = tid & 63;
    const int quad = lane >> 4, lm = lane & 15;
    const int wm = w & 1, wn = w >> 1;
    const int n0 = blockIdx.x * 64;
    const int m0 = blockIdx.y * 128;

    const int arow = lane >> 2;
    const int sch = (lane & 3) ^ ((lane >> 3) & 3);
    const u16* agp0 = Wp + (size_t)(m0 + w * 16 + arow) * 512 + sch * 8;
    const u16* agp1 = agp0 + (size_t)64 * 512;
    const u16* bgp = Ot + (size_t)(n0 + w * 16 + arow) * 512 + sch * 8;

    async16(agp0, &Al[0][w * 16 * 32]);
    async16(agp1, &Al[0][(64 + w * 16) * 32]);
    async16(bgp, &Bl[0][w * 16 * 32]);
    agp0 += 32; agp1 += 32; bgp += 32;

    const int FOFF = lm * 64 + ((quad ^ ((lm >> 1) & 3)) << 4);

    f32x4 acc[4][2];
#pragma unroll
    for (int mt = 0; mt < 4; ++mt)
#pragma unroll
        for (int bt = 0; bt < 2; ++bt) acc[mt][bt] = (f32x4){0.f, 0.f, 0.f, 0.f};

    __syncthreads();

    for (int s = 0; s < 16; ++s) {
        const int buf = s & 1;
        if (s < 15) {
            async16(agp0, &Al[buf ^ 1][w * 16 * 32]);
            async16(agp1, &Al[buf ^ 1][(64 + w * 16) * 32]);
            async16(bgp, &Bl[buf ^ 1][w * 16 * 32]);
            agp0 += 32; agp1 += 32; bgp += 32;
        }
        const char* Ab = (const char*)&Al[buf][0];
        const char* Bb = (const char*)&Bl[buf][0];
        bf16x8 af[4], bfr[2];
#pragma unroll
        for (int mt = 0; mt < 4; ++mt)
            af[mt] = *(const bf16x8*)(Ab + wm * 4096 + mt * 1024 + FOFF);
#pragma unroll
        for (int bt = 0; bt < 2; ++bt)
            bfr[bt] = *(const bf16x8*)(Bb + wn * 2048 + bt * 1024 + FOFF);
#pragma unroll
        for (int mt = 0; mt < 4; ++mt)
#pragma unroll
            for (int bt = 0; bt < 2; ++bt)
                acc[mt][bt] = MFMA16(af[mt], bfr[bt], acc[mt][bt]);
        __syncthreads();
    }

#pragma unroll
    for (int mt = 0; mt < 4; ++mt) {
        const int ch = m0 + wm * 64 + mt * 16 + quad * 4;
        float4 bv = *(const float4*)(pb + ch);
        float bvf[4] = {bv.x, bv.y, bv.z, bv.w};
#pragma unroll
        for (int bt = 0; bt < 2; ++bt) {
            int tok = n0 + wn * 32 + bt * 16 + lm;
#pragma unroll
            for (int r = 0; r < 4; ++r)
                out[(size_t)(ch + r) * 4096 + tok] = acc[mt][bt][r] + bvf[r];
        }
    }
}

// ---------------------------------------------------------------------------
// Flash attention v12: R10 structure with V MOVED OFF THE ASYNC PATH.
// R11 post-mortem: identity staging (fewer, fully-sequential L2 requests)
// did NOT help -> not request-rate-bound. Cross-check vs guide GEMM data:
// m97 stages 2.1GB/157us = 13.4 TB/s, m201 = 12.2 TB/s, our flash
// 512MB/48us = 10.7 TB/s -> the global_load_lds path itself saturates
// ~11-13 TB/s chip-wide (well under the 34.5 TB/s regular-load L2 ceiling).
// v12 splits traffic across paths: K stays on async staging (256 MB), V
// fragments load via regular ldg8 (256 MB, R2-proven global addressing)
// pipelined one tile ahead (loaded body t, consumed by PV at body t+1 via
// the existing pv=nv carry -> ~1900 cyc cover; compiler inserts exact
// counted vmcnt for its own loads). vmcnt ledger (4-op K stage, dist 2):
// prologue [Q8,b2,K0(4),K1(4)]; body0 wait(4); steady wait(10) =
// V(4)+b(2)+Kstage(4); t31 wait(6). Everything else identical to R10:
// barrier-free private quarters, head-clustered grid 512, A0/A1 K frags,
// bb pack, split-K=4 merge. LDS staging drops to 32 KB (K only).
// ---------------------------------------------------------------------------
#define WAITVM(N) asm volatile("s_waitcnt vmcnt(" #N ")" ::: "memory")

__global__ __launch_bounds__(256, 2) void flash_attn(const u16* __restrict__ Qt,
                                                     const u16* __restrict__ Kt,
                                                     const u16* __restrict__ Vp,
                                                     const float* __restrict__ lqw2g,
                                                     u16* __restrict__ Ot) {
    __shared__ __align__(16) char smem[65536];

    const int tid = threadIdx.x;
    const int w = tid >> 6, lane = tid & 63;         // w = 0..3 (key quarter)
    const int quad = lane >> 4, lm = lane & 15;
    const int bid = blockIdx.x;
    const int h = bid & 7, hq = h * 64;              // head -> XCD cluster
    const int q0 = (bid >> 3) * 64;
    const int kstart = w * 1024;

    char* kvw = smem + w * 8192;                     // private K dbuf (2 x 4 KB)

    // K staging (XOR swizzle at global source, LDS linear)
    const int srow = lane >> 3;                      // 0..7
    const int schunk = (lane & 7) ^ srow;
    const u16* kg = Kt + (size_t)(kstart + srow) * 512 + hq + schunk * 8;

    // V fragment base (direct-global; R2-proven layout)
    const u16* vp = Vp + (size_t)(hq + lm) * 4096 + kstart + quad * 8;

    // Q fragments: 4 subtiles x 2 d-halves (8 vmem loads)
    bf16x8 bq0[4], bq1[4];
#pragma unroll
    for (int s = 0; s < 4; ++s) {
        const u16* qb = Qt + (size_t)(q0 + s * 16 + lm) * 512 + hq + quad * 8;
        bq0[s] = ldg8(qb);
        bq1[s] = ldg8(qb + 32);
    }

    // bias prefetch registers (2 vmem loads)
    f32x4 breg0 = *(const f32x4*)(lqw2g + kstart + quad * 4);
    f32x4 breg1 = *(const f32x4*)(lqw2g + kstart + 16 + quad * 4);
    const float* bptr = lqw2g + kstart + 32 + quad * 4;

    // K fragment read offsets (proven layout)
    const int A0 = lm * 128 + ((quad ^ (lm & 7)) << 4);       // d 0..31
    const int A1 = A0 ^ 64;                                   // d 32..63

#define STAGEK(DST)                                                            \
    {                                                                          \
        char* nb = (DST);                                                      \
        async16(kg, nb);                                                       \
        async16(kg + 8 * 512, nb + 1024);                                      \
        async16(kg + 16 * 512, nb + 2048);                                     \
        async16(kg + 24 * 512, nb + 3072);                                     \
        kg += 32 * 512;                                                        \
    }

    // stage K tiles 0 and 1
    STAGEK(kvw)
    STAGEK(kvw + 4096)

    union { u32 u[4]; bf16x8 v; } onesu;
    onesu.u[0] = onesu.u[1] = onesu.u[2] = onesu.u[3] = 0x3F803F80u;
    const bf16x8 onesv = onesu.v;

    f32x4 acc_o[4][4];                                // [d-group][q-sub]
#pragma unroll
    for (int mt = 0; mt < 4; ++mt)
#pragma unroll
        for (int s = 0; s < 4; ++s) acc_o[mt][s] = (f32x4){0.f, 0.f, 0.f, 0.f};
    f32x4 acc_l[4];
#pragma unroll
    for (int s = 0; s < 4; ++s) acc_l[s] = (f32x4){0.f, 0.f, 0.f, 0.f};

    // loop-carried pipeline state: P (bb) and V frags of the previous tile
    union { u32 u[4]; bf16x8 v; } pb_[4];
    bf16x8 pv0, pv1, pv2, pv3;
    int bufsel = 0;

#define BODY(WN, DOBIAS, DOSTAGE, DOPV)                                        \
    {                                                                          \
        WAITVM(WN);                                                            \
        bf16x8 nv0 = ldg8(vp);                                                 \
        bf16x8 nv1 = ldg8(vp + (size_t)16 * 4096);                             \
        bf16x8 nv2 = ldg8(vp + (size_t)32 * 4096);                             \
        bf16x8 nv3 = ldg8(vp + (size_t)48 * 4096);                             \
        vp += 32;                                                              \
        const char* Kb = kvw + bufsel;                                         \
        bf16x8 k00 = *(const bf16x8*)(Kb + A0);                                \
        bf16x8 k01 = *(const bf16x8*)(Kb + A1);                                \
        bf16x8 k10 = *(const bf16x8*)(Kb + 2048 + A0);                         \
        bf16x8 k11 = *(const bf16x8*)(Kb + 2048 + A1);                         \
        if (DOPV) {                                                            \
            _Pragma("unroll")                                                  \
            for (int s = 0; s < 4; ++s) {                                      \
                acc_o[0][s] = MFMA16(pv0, pb_[s].v, acc_o[0][s]);              \
                acc_o[1][s] = MFMA16(pv1, pb_[s].v, acc_o[1][s]);              \
                acc_o[2][s] = MFMA16(pv2, pb_[s].v, acc_o[2][s]);              \
                acc_o[3][s] = MFMA16(pv3, pb_[s].v, acc_o[3][s]);              \
                acc_l[s] = MFMA16(onesv, pb_[s].v, acc_l[s]);                  \
            }                                                                  \
        }                                                                      \
        _Pragma("unroll")                                                      \
        for (int s = 0; s < 4; ++s) {                                          \
            f32x4 a = MFMA16(k00, bq0[s], breg0);                              \
            a = MFMA16(k01, bq1[s], a);                                        \
            pb_[s].u[0] = pack2(EXP2F(a[0]), EXP2F(a[1]));                     \
            pb_[s].u[1] = pack2(EXP2F(a[2]), EXP2F(a[3]));                     \
        }                                                                      \
        _Pragma("unroll")                                                      \
        for (int s = 0; s < 4; ++s) {                                          \
            f32x4 c = MFMA16(k10, bq0[s], breg1);                              \
            c = MFMA16(k11, bq1[s], c);                                        \
            pb_[s].u[2] = pack2(EXP2F(c[0]), EXP2F(c[1]));                     \
            pb_[s].u[3] = pack2(EXP2F(c[2]), EXP2F(c[3]));                     \
        }                                                                      \
        if (DOBIAS) {                                                          \
            breg0 = *(const f32x4*)(bptr);                                     \
            breg1 = *(const f32x4*)(bptr + 16);                                \
            bptr += 32;                                                        \
        }                                                                      \
        pv0 = nv0; pv1 = nv1; pv2 = nv2; pv3 = nv3;                            \
        if (DOSTAGE) STAGEK(kvw + bufsel)                                      \
        bufsel ^= 4096;                                                        \
    }

    BODY(4, true, true, false)                 // t = 0: QK only (peel)
    for (int t = 1; t < 30; ++t)
        BODY(10, true, true, true)             // t = 1..29: PV_{t-1} + QK_t
    BODY(10, true, false, true)                // t = 30 (bias_31, no stage)
    BODY(6, false, false, true)                // t = 31

#undef BODY
#undef STAGEK

    // epilogue: PV for tile 31
#pragma unroll
    for (int s = 0; s < 4; ++s) {
        acc_o[0][s] = MFMA16(pv0, pb_[s].v, acc_o[0][s]);
        acc_o[1][s] = MFMA16(pv1, pb_[s].v, acc_o[1][s]);
        acc_o[2][s] = MFMA16(pv2, pb_[s].v, acc_o[2][s]);
        acc_o[3][s] = MFMA16(pv3, pb_[s].v, acc_o[3][s]);
        acc_l[s] = MFMA16(onesv, pb_[s].v, acc_l[s]);
    }

    // ---- split-K merge: pure add (max-free softmax), 4-way ----
    __syncthreads();                           // staging LDS now dead
    float* mbuf = (float*)smem;
    if (w != 0) {
        float* ob = mbuf + (w - 1) * 4096;     // 64 q x 64 d fp32
#pragma unroll
        for (int s = 0; s < 4; ++s) {
            const int r = s * 16 + lm;
#pragma unroll
            for (int mt = 0; mt < 4; ++mt) {
                const int sl = (mt * 4 + quad) ^ lm;
                *(f32x4*)(ob + r * 64 + sl * 4) = acc_o[mt][s];
            }
        }
        if (quad == 0) {
#pragma unroll
            for (int s = 0; s < 4; ++s)
                mbuf[12288 + (w - 1) * 64 + s * 16 + lm] = acc_l[s][0];
        }
    }
    __syncthreads();
    if (w != 0) return;

#pragma unroll
    for (int s = 0; s < 4; ++s) {
        const int r = s * 16 + lm;
        float lsum = acc_l[s][0];
#pragma unroll
        for (int p = 0; p < 3; ++p)
            lsum += mbuf[12288 + p * 64 + r];
        const float inv = 1.0f / lsum;
#pragma unroll
        for (int mt = 0; mt < 4; ++mt) {
            const int sl = (mt * 4 + quad) ^ lm;
            f32x4 o = acc_o[mt][s];
#pragma unroll
            for (int p = 0; p < 3; ++p)
                o += *(const f32x4*)(mbuf + p * 4096 + r * 64 + sl * 4);
            u16x4 pkv;
#pragma unroll
            for (int r2 = 0; r2 < 4; ++r2)
                pkv[r2] = f2bf(o[r2] * inv);
            *reinterpret_cast<u16x4*>(Ot + (size_t)(q0 + r) * 512 +
                                      hq + mt * 16 + quad * 4) = pkv;
        }
    }
}

// ---------------------------------------------------------------------------
extern "C" void kernel_launch(void* const* d_in, const int* in_sizes, int n_in,
                              void* d_out, int out_size, void* d_ws, size_t ws_size,
                              hipStream_t stream) {
    (void)in_sizes; (void)n_in; (void)out_size; (void)ws_size;
    const float* X   = (const float*)d_in[0];
    const float* qw  = (const float*)d_in[1];
    const float* qb  = (const float*)d_in[2];
    const float* kw  = (const float*)d_in[3];
    const float* kb  = (const float*)d_in[4];
    const float* vw  = (const float*)d_in[5];
    const float* vb  = (const float*)d_in[6];
    const float* pw  = (const float*)d_in[7];
    const float* pb  = (const float*)d_in[8];
    const float* lqw = (const float*)d_in[9];

    const size_t E = (size_t)4096 * 512;
    const size_t WE = (size_t)512 * 512;
    u16* Xt    = (u16*)d_ws;
    u16* Qt    = Xt + E;
    u16* Kt    = Qt + E;
    u16* Vp    = Kt + E;
    u16* Wqkv  = Vp + E;          // 1536 x 512 stacked
    u16* Wp    = Wqkv + 3 * WE;
    float* lqw2g = (float*)(Wp + WE);   // 4096 fp32, 16B-aligned
    u16* Ot    = Xt;              // reuse (dead after qkv)

    prep<<<dim3(64, 13), dim3(256), 0, stream>>>(X, Xt, qw, kw, vw, pw,
                                                 Wqkv, Wp, lqw, lqw2g);
    qkv_gemm<<<dim3(32, 12), dim3(512), 0, stream>>>(Wqkv, Xt, qb, kb, vb, Qt, Kt, Vp);
    flash_attn<<<dim3(512), dim3(256), 0, stream>>>(Qt, Kt, Vp, lqw2g, Ot);
    out_gemm<<<dim3(64, 4), dim3(256), 0, stream>>>(Wp, Ot, pb, (float*)d_out);
}

// Round 13
// 77.391 us; speedup vs baseline: 1.0739x; 1.0739x over previous
//
#include <hip/hip_runtime.h>

typedef unsigned short u16;
typedef unsigned int u32;
typedef __bf16 bf16x8 __attribute__((ext_vector_type(8)));
typedef float f32x4 __attribute__((ext_vector_type(4)));
typedef unsigned short u16x4 __attribute__((ext_vector_type(4)));

#define LOG2E 1.4426950408889634f

#if __has_builtin(__builtin_amdgcn_exp2f)
#define EXP2F(x) __builtin_amdgcn_exp2f(x)
#else
#define EXP2F(x) exp2f(x)
#endif

__device__ __forceinline__ u16 f2bf(float f) {
    union { float f; u32 u; } a; a.f = f;
    u32 u = a.u;
    u += 0x7FFFu + ((u >> 16) & 1u);   // RNE (finite inputs)
    return (u16)(u >> 16);
}
__device__ __forceinline__ bf16x8 ldg8(const u16* p) {
    return *reinterpret_cast<const bf16x8*>(p);
}
#if __has_builtin(__builtin_amdgcn_cvt_pk_bf16_f32)
__device__ __forceinline__ u32 pack2(float a, float b) {
    auto r = __builtin_amdgcn_cvt_pk_bf16_f32(a, b);   // v_cvt_pk_bf16_f32
    return __builtin_bit_cast(u32, r);
}
#else
__device__ __forceinline__ u32 pack2(float a, float b) {
    u32 ua = __float_as_uint(a) + 0x8000u;
    u32 ub = __float_as_uint(b) + 0x8000u;
    return __builtin_amdgcn_perm(ub, ua, 0x07060302);
}
#endif
// async global -> LDS, 16 B per lane. LDS dest = wave-uniform base + lane*16.
__device__ __forceinline__ void async16(const void* g, void* l) {
    __builtin_amdgcn_global_load_lds(
        (const __attribute__((address_space(1))) u32*)g,
        (__attribute__((address_space(3))) u32*)l, 16, 0, 0);
}

#define MFMA16(a, b, c) __builtin_amdgcn_mfma_f32_16x16x32_bf16((a), (b), (c), 0, 0, 0)

// ---------------------------------------------------------------------------
// Fused prep: y<8 -> transpose X tile; y in 8..11 -> pack weight matrix;
// y==12 -> lqw * log2(e) into global fp32 (4 blocks). Grid (64, 13).
// ---------------------------------------------------------------------------
__global__ __launch_bounds__(256) void prep(const float* __restrict__ X,
                                            u16* __restrict__ Xt,
                                            const float* __restrict__ s0,
                                            const float* __restrict__ s1,
                                            const float* __restrict__ s2,
                                            const float* __restrict__ s3,
                                            u16* __restrict__ Wqkv,
                                            u16* __restrict__ Wp,
                                            const float* __restrict__ lqw,
                                            float* __restrict__ lqw2g) {
    __shared__ u16 tile[64][65];
    const int tid = threadIdx.x;
    const int y = blockIdx.y;

    if (y < 8) {                                  // transpose 64x64 tile
        const int t0 = blockIdx.x * 64;
        const int c0 = y * 64;
#pragma unroll
        for (int i = 0; i < 16; ++i) {
            int idx = tid + i * 256;
            int r = idx >> 6, cc = idx & 63;
            tile[r][cc] = f2bf(X[(size_t)(c0 + r) * 4096 + t0 + cc]);
        }
        __syncthreads();
#pragma unroll
        for (int i = 0; i < 16; ++i) {
            int idx = tid + i * 256;
            int tr = idx >> 6, cc = idx & 63;
            Xt[(size_t)(t0 + tr) * 512 + c0 + cc] = tile[cc][tr];
        }
    } else if (y < 12) {                          // pack one 512x512 weight
        const int m = y - 8;
        const float* s = (m == 0) ? s0 : (m == 1) ? s1 : (m == 2) ? s2 : s3;
        u16* d = (m == 3) ? Wp : Wqkv + (size_t)m * 262144;
#pragma unroll
        for (int j = 0; j < 4; ++j) {
            int i = blockIdx.x * 1024 + j * 256 + tid;
            float4 v = reinterpret_cast<const float4*>(s)[i];
            u16x4 o;
            o[0] = f2bf(v.x); o[1] = f2bf(v.y); o[2] = f2bf(v.z); o[3] = f2bf(v.w);
            reinterpret_cast<u16x4*>(d)[i] = o;
        }
    } else {                                      // lqw * LOG2E (1024 float4)
        if (blockIdx.x < 4) {
            int i = blockIdx.x * 256 + tid;
            float4 v = reinterpret_cast<const float4*>(lqw)[i];
            v.x *= LOG2E; v.y *= LOG2E; v.z *= LOG2E; v.w *= LOG2E;
            reinterpret_cast<float4*>(lqw2g)[i] = v;
        }
    }
}

// ---------------------------------------------------------------------------
// Fused QKV GEMM, LDS-staged. Qt/Kt token-major (unchanged, known-good).
// V is written into a FRAG-MAJOR image Vimg[head][tile][fragX][lane][8 u16]
// so the flash kernel's V fragments are perfectly coalesced 1KB wave reads
// on the regular (non-async) load path. Mapping derived by inverting the
// R1/R11-proven AV LDS layout (samples D=0/1/17 hand-verified):
//   X = D>>4, lane = kc*16 + ((D>>1)&7)*2 + (D&1), reg = key2&7
// with key2/t from the R11-verified column permutation.
// ---------------------------------------------------------------------------
__global__ __launch_bounds__(512, 2) void qkv_gemm(const u16* __restrict__ Wqkv,
                                                   const u16* __restrict__ Xt,
                                                   const float* __restrict__ qb,
                                                   const float* __restrict__ kb,
                                                   const float* __restrict__ vb,
                                                   u16* __restrict__ Qt,
                                                   u16* __restrict__ Kt,
                                                   u16* __restrict__ Vimg) {
    __shared__ __align__(16) u16 Al[2][128 * 32];
    __shared__ __align__(16) u16 Bl[2][128 * 32];

    const int tid = threadIdx.x;
    const int w = tid >> 6, lane = tid & 63;
    const int quad = lane >> 4, lm = lane & 15;
    const int wm = w & 1, wn = w >> 1;
    const int n0 = blockIdx.x * 128;
    const int my = blockIdx.y;
    const int m0 = my * 128;

    const int arow = lane >> 2;
    const int sch = (lane & 3) ^ ((lane >> 3) & 3);   // source chunk (XOR on row>>1)
    const u16* agp = Wqkv + (size_t)(m0 + w * 16 + arow) * 512 + sch * 8;
    const u16* bgp = Xt + (size_t)(n0 + w * 16 + arow) * 512 + sch * 8;

    async16(agp, &Al[0][w * 16 * 32]);
    async16(bgp, &Bl[0][w * 16 * 32]);
    agp += 32; bgp += 32;

    const int FOFF = lm * 64 + ((quad ^ ((lm >> 1) & 3)) << 4);

    f32x4 acc[4][2];
#pragma unroll
    for (int mt = 0; mt < 4; ++mt)
#pragma unroll
        for (int bt = 0; bt < 2; ++bt) acc[mt][bt] = (f32x4){0.f, 0.f, 0.f, 0.f};

    __syncthreads();

    for (int s = 0; s < 16; ++s) {
        const int buf = s & 1;
        if (s < 15) {
            async16(agp, &Al[buf ^ 1][w * 16 * 32]);
            async16(bgp, &Bl[buf ^ 1][w * 16 * 32]);
            agp += 32; bgp += 32;
        }
        const char* Ab = (const char*)&Al[buf][0];
        const char* Bb = (const char*)&Bl[buf][0];
        bf16x8 af[4], bfr[2];
#pragma unroll
        for (int mt = 0; mt < 4; ++mt)
            af[mt] = *(const bf16x8*)(Ab + wm * 4096 + mt * 1024 + FOFF);
#pragma unroll
        for (int bt = 0; bt < 2; ++bt)
            bfr[bt] = *(const bf16x8*)(Bb + wn * 2048 + bt * 1024 + FOFF);
#pragma unroll
        for (int mt = 0; mt < 4; ++mt)
#pragma unroll
            for (int bt = 0; bt < 2; ++bt)
                acc[mt][bt] = MFMA16(af[mt], bfr[bt], acc[mt][bt]);
        __syncthreads();
    }

    const int mat = my >> 2;                     // 0=Q, 1=K, 2=V
    const float* bias = (mat == 0) ? qb : (mat == 1) ? kb : vb;
    const int chbase = (my & 3) * 128 + wm * 64 + quad * 4;

    if (mat < 2) {
        u16* out = mat ? Kt : Qt;
        const float sc = mat ? 1.0f : 0.125f * LOG2E;
#pragma unroll
        for (int mt = 0; mt < 4; ++mt) {
            const int ch = chbase + mt * 16;
            float4 bv = *(const float4*)(bias + ch);
            float bvf[4] = {bv.x, bv.y, bv.z, bv.w};
#pragma unroll
            for (int bt = 0; bt < 2; ++bt) {
                int tok = n0 + wn * 32 + bt * 16 + lm;
                u16x4 pk;
#pragma unroll
                for (int r = 0; r < 4; ++r)
                    pk[r] = f2bf((acc[mt][bt][r] + bvf[r]) * sc);
                *(u16x4*)(out + (size_t)tok * 512 + ch) = pk;
            }
        }
    } else {
        // V -> frag-major image
#pragma unroll
        for (int mt = 0; mt < 4; ++mt) {
            const int ch = chbase + mt * 16;
            float4 bv = *(const float4*)(bias + ch);
            float bvf[4] = {bv.x, bv.y, bv.z, bv.w};
            const int hh = ch >> 6;
            const int D0 = ch & 63;
#pragma unroll
            for (int bt = 0; bt < 2; ++bt) {
                int g = bt * 16 + lm;
                int key2 = 8 * ((g >> 2) & 3) + 4 * ((g >> 4) & 1) + (g & 3);
                int t = (n0 >> 5) + wn;
                int kc = key2 >> 3, ke = key2 & 7;
                u16* vdst = Vimg + (size_t)(hh * 128 + t) * 2048 + ke;
#pragma unroll
                for (int r = 0; r < 4; ++r) {
                    int D = D0 + r;
                    int lane_i = kc * 16 + ((D >> 1) & 7) * 2 + (D & 1);
                    vdst[(size_t)(D >> 4) * 512 + lane_i * 8] = f2bf(acc[mt][bt][r] + bvf[r]);
                }
            }
        }
    }
}

// ---------------------------------------------------------------------------
// Output projection, LDS-staged (unchanged, known-good).
// ---------------------------------------------------------------------------
__global__ __launch_bounds__(256, 2) void out_gemm(const u16* __restrict__ Wp,
                                                   const u16* __restrict__ Ot,
                                                   const float* __restrict__ pb,
                                                   float* __restrict__ out) {
    __shared__ __align__(16) u16 Al[2][128 * 32];
    __shared__ __align__(16) u16 Bl[2][64 * 32];

    const int tid = threadIdx.x;
    const int w = tid >> 6, lane = tid & 63;
    const int quad = lane >> 4, lm = lane & 15;
    const int wm = w & 1, wn = w >> 1;
    const int n0 = blockIdx.x * 64;
    const int m0 = blockIdx.y * 128;

    const int arow = lane >> 2;
    const int sch = (lane & 3) ^ ((lane >> 3) & 3);
    const u16* agp0 = Wp + (size_t)(m0 + w * 16 + arow) * 512 + sch * 8;
    const u16* agp1 = agp0 + (size_t)64 * 512;
    const u16* bgp = Ot + (size_t)(n0 + w * 16 + arow) * 512 + sch * 8;

    async16(agp0, &Al[0][w * 16 * 32]);
    async16(agp1, &Al[0][(64 + w * 16) * 32]);
    async16(bgp, &Bl[0][w * 16 * 32]);
    agp0 += 32; agp1 += 32; bgp += 32;

    const int FOFF = lm * 64 + ((quad ^ ((lm >> 1) & 3)) << 4);

    f32x4 acc[4][2];
#pragma unroll
    for (int mt = 0; mt < 4; ++mt)
#pragma unroll
        for (int bt = 0; bt < 2; ++bt) acc[mt][bt] = (f32x4){0.f, 0.f, 0.f, 0.f};

    __syncthreads();

    for (int s = 0; s < 16; ++s) {
        const int buf = s & 1;
        if (s < 15) {
            async16(agp0, &Al[buf ^ 1][w * 16 * 32]);
            async16(agp1, &Al[buf ^ 1][(64 + w * 16) * 32]);
            async16(bgp, &Bl[buf ^ 1][w * 16 * 32]);
            agp0 += 32; agp1 += 32; bgp += 32;
        }
        const char* Ab = (const char*)&Al[buf][0];
        const char* Bb = (const char*)&Bl[buf][0];
        bf16x8 af[4], bfr[2];
#pragma unroll
        for (int mt = 0; mt < 4; ++mt)
            af[mt] = *(const bf16x8*)(Ab + wm * 4096 + mt * 1024 + FOFF);
#pragma unroll
        for (int bt = 0; bt < 2; ++bt)
            bfr[bt] = *(const bf16x8*)(Bb + wn * 2048 + bt * 1024 + FOFF);
#pragma unroll
        for (int mt = 0; mt < 4; ++mt)
#pragma unroll
            for (int bt = 0; bt < 2; ++bt)
                acc[mt][bt] = MFMA16(af[mt], bfr[bt], acc[mt][bt]);
        __syncthreads();
    }

#pragma unroll
    for (int mt = 0; mt < 4; ++mt) {
        const int ch = m0 + wm * 64 + mt * 16 + quad * 4;
        float4 bv = *(const float4*)(pb + ch);
        float bvf[4] = {bv.x, bv.y, bv.z, bv.w};
#pragma unroll
        for (int bt = 0; bt < 2; ++bt) {
            int tok = n0 + wn * 32 + bt * 16 + lm;
#pragma unroll
            for (int r = 0; r < 4; ++r)
                out[(size_t)(ch + r) * 4096 + tok] = acc[mt][bt][r] + bvf[r];
        }
    }
}

// ---------------------------------------------------------------------------
// Flash attention v14: PATH-SPLIT with coalesced V.
// R12 post-mortem: V-direct was slower because its loads were 16 scattered
// 64B segments/instr (same pattern as R2), not because the regular path is
// slow. Byte-rate law across all rounds: async-staged bytes move at
// ~11-13 TB/s (matches guide m97 13.4 / m201 12.2 TB/s) -> the async path
// is the saturated resource. v14 keeps K on the async path (256 MB) and
// reads V from a frag-major image (qkv pre-baked) via regular ldg8: each
// V fragment = one fully-sequential 1KB wave read (8x128B lines),
// streaming, L2-resident -> V's 256 MB rides the L1/vector path
// concurrently. In-body pipeline carry (pv=nv) provides latency cover.
// Tail waits fixed (R12's t30/t31 retired nothing - latent race):
// body0 wait(4) [FIFO Q8+b2+K0(4)+K1(4)=18 -> retire thru K0];
// steady wait(10) [K_t(4)+b(2)+K_{t+1}(4)]; t30 wait(6); t31 wait(2).
// Everything else identical to R12/R10: barrier-free private key-quarters,
// head-clustered grid 512, A0/A1 K frags, split-K=4 merge. LDS 32 KB stage.
// ---------------------------------------------------------------------------
#define WAITVM(N) asm volatile("s_waitcnt vmcnt(" #N ")" ::: "memory")

__global__ __launch_bounds__(256, 2) void flash_attn(const u16* __restrict__ Qt,
                                                     const u16* __restrict__ Kt,
                                                     const u16* __restrict__ Vimg,
                                                     const float* __restrict__ lqw2g,
                                                     u16* __restrict__ Ot) {
    __shared__ __align__(16) char smem[65536];

    const int tid = threadIdx.x;
    const int w = tid >> 6, lane = tid & 63;         // w = 0..3 (key quarter)
    const int quad = lane >> 4, lm = lane & 15;
    const int bid = blockIdx.x;
    const int h = bid & 7, hq = h * 64;              // head -> XCD cluster
    const int q0 = (bid >> 3) * 64;
    const int kstart = w * 1024;

    char* kvw = smem + w * 8192;                     // private K dbuf (2 x 4 KB)

    // K staging (XOR swizzle at global source, LDS linear)
    const int srow = lane >> 3;                      // 0..7
    const int schunk = (lane & 7) ^ srow;
    const u16* kg = Kt + (size_t)(kstart + srow) * 512 + hq + schunk * 8;

    // V frag-major image: tile = 2048 u16; frag X at +X*512; lane at +lane*8
    const u16* vp = Vimg + (size_t)(h * 128 + w * 32) * 2048 + (size_t)lane * 8;

    // Q fragments: 4 subtiles x 2 d-halves (8 vmem loads)
    bf16x8 bq0[4], bq1[4];
#pragma unroll
    for (int s = 0; s < 4; ++s) {
        const u16* qb = Qt + (size_t)(q0 + s * 16 + lm) * 512 + hq + quad * 8;
        bq0[s] = ldg8(qb);
        bq1[s] = ldg8(qb + 32);
    }

    // bias prefetch registers (2 vmem loads)
    f32x4 breg0 = *(const f32x4*)(lqw2g + kstart + quad * 4);
    f32x4 breg1 = *(const f32x4*)(lqw2g + kstart + 16 + quad * 4);
    const float* bptr = lqw2g + kstart + 32 + quad * 4;

    // K fragment read offsets (proven layout)
    const int A0 = lm * 128 + ((quad ^ (lm & 7)) << 4);       // d 0..31
    const int A1 = A0 ^ 64;                                   // d 32..63

#define STAGEK(DST)                                                            \
    {                                                                          \
        char* nb = (DST);                                                      \
        async16(kg, nb);                                                       \
        async16(kg + 8 * 512, nb + 1024);                                      \
        async16(kg + 16 * 512, nb + 2048);                                     \
        async16(kg + 24 * 512, nb + 3072);                                     \
        kg += 32 * 512;                                                        \
    }

    // stage K tiles 0 and 1
    STAGEK(kvw)
    STAGEK(kvw + 4096)

    union { u32 u[4]; bf16x8 v; } onesu;
    onesu.u[0] = onesu.u[1] = onesu.u[2] = onesu.u[3] = 0x3F803F80u;
    const bf16x8 onesv = onesu.v;

    f32x4 acc_o[4][4];                                // [d-group][q-sub]
#pragma unroll
    for (int mt = 0; mt < 4; ++mt)
#pragma unroll
        for (int s = 0; s < 4; ++s) acc_o[mt][s] = (f32x4){0.f, 0.f, 0.f, 0.f};
    f32x4 acc_l[4];
#pragma unroll
    for (int s = 0; s < 4; ++s) acc_l[s] = (f32x4){0.f, 0.f, 0.f, 0.f};

    // loop-carried pipeline state: P (bb) and V frags of the previous tile
    union { u32 u[4]; bf16x8 v; } pb_[4];
    bf16x8 pv0, pv1, pv2, pv3;
    int bufsel = 0;

#define BODY(WN, DOBIAS, DOSTAGE, DOPV)                                        \
    {                                                                          \
        WAITVM(WN);                                                            \
        bf16x8 nv0 = ldg8(vp);                                                 \
        bf16x8 nv1 = ldg8(vp + 512);                                           \
        bf16x8 nv2 = ldg8(vp + 1024);                                          \
        bf16x8 nv3 = ldg8(vp + 1536);                                          \
        vp += 2048;                                                            \
        const char* Kb = kvw + bufsel;                                         \
        bf16x8 k00 = *(const bf16x8*)(Kb + A0);                                \
        bf16x8 k01 = *(const bf16x8*)(Kb + A1);                                \
        bf16x8 k10 = *(const bf16x8*)(Kb + 2048 + A0);                         \
        bf16x8 k11 = *(const bf16x8*)(Kb + 2048 + A1);                         \
        if (DOPV) {                                                            \
            _Pragma("unroll")                                                  \
            for (int s = 0; s < 4; ++s) {                                      \
                acc_o[0][s] = MFMA16(pv0, pb_[s].v, acc_o[0][s]);              \
                acc_o[1][s] = MFMA16(pv1, pb_[s].v, acc_o[1][s]);              \
                acc_o[2][s] = MFMA16(pv2, pb_[s].v, acc_o[2][s]);              \
                acc_o[3][s] = MFMA16(pv3, pb_[s].v, acc_o[3][s]);              \
                acc_l[s] = MFMA16(onesv, pb_[s].v, acc_l[s]);                  \
            }                                                                  \
        }                                                                      \
        _Pragma("unroll")                                                      \
        for (int s = 0; s < 4; ++s) {                                          \
            f32x4 a = MFMA16(k00, bq0[s], breg0);                              \
            a = MFMA16(k01, bq1[s], a);                                        \
            pb_[s].u[0] = pack2(EXP2F(a[0]), EXP2F(a[1]));                     \
            pb_[s].u[1] = pack2(EXP2F(a[2]), EXP2F(a[3]));                     \
        }                                                                      \
        _Pragma("unroll")                                                      \
        for (int s = 0; s < 4; ++s) {                                          \
            f32x4 c = MFMA16(k10, bq0[s], breg1);                              \
            c = MFMA16(k11, bq1[s], c);                                        \
            pb_[s].u[2] = pack2(EXP2F(c[0]), EXP2F(c[1]));                     \
            pb_[s].u[3] = pack2(EXP2F(c[2]), EXP2F(c[3]));                     \
        }                                                                      \
        if (DOBIAS) {                                                          \
            breg0 = *(const f32x4*)(bptr);                                     \
            breg1 = *(const f32x4*)(bptr + 16);                                \
            bptr += 32;                                                        \
        }                                                                      \
        pv0 = nv0; pv1 = nv1; pv2 = nv2; pv3 = nv3;                            \
        if (DOSTAGE) STAGEK(kvw + bufsel)                                      \
        bufsel ^= 4096;                                                        \
    }

    BODY(4, true, true, false)                 // t = 0: QK only (peel)
    for (int t = 1; t < 30; ++t)
        BODY(10, true, true, true)             // t = 1..29: PV_{t-1} + QK_t
    BODY(6, true, false, true)                 // t = 30 (bias_31, no stage)
    BODY(2, false, false, true)                // t = 31

#undef BODY
#undef STAGEK

    // epilogue: PV for tile 31
#pragma unroll
    for (int s = 0; s < 4; ++s) {
        acc_o[0][s] = MFMA16(pv0, pb_[s].v, acc_o[0][s]);
        acc_o[1][s] = MFMA16(pv1, pb_[s].v, acc_o[1][s]);
        acc_o[2][s] = MFMA16(pv2, pb_[s].v, acc_o[2][s]);
        acc_o[3][s] = MFMA16(pv3, pb_[s].v, acc_o[3][s]);
        acc_l[s] = MFMA16(onesv, pb_[s].v, acc_l[s]);
    }

    // ---- split-K merge: pure add (max-free softmax), 4-way ----
    __syncthreads();                           // staging LDS now dead
    float* mbuf = (float*)smem;
    if (w != 0) {
        float* ob = mbuf + (w - 1) * 4096;     // 64 q x 64 d fp32
#pragma unroll
        for (int s = 0; s < 4; ++s) {
            const int r = s * 16 + lm;
#pragma unroll
            for (int mt = 0; mt < 4; ++mt) {
                const int sl = (mt * 4 + quad) ^ lm;
                *(f32x4*)(ob + r * 64 + sl * 4) = acc_o[mt][s];
            }
        }
        if (quad == 0) {
#pragma unroll
            for (int s = 0; s < 4; ++s)
                mbuf[12288 + (w - 1) * 64 + s * 16 + lm] = acc_l[s][0];
        }
    }
    __syncthreads();
    if (w != 0) return;

#pragma unroll
    for (int s = 0; s < 4; ++s) {
        const int r = s * 16 + lm;
        float lsum = acc_l[s][0];
#pragma unroll
        for (int p = 0; p < 3; ++p)
            lsum += mbuf[12288 + p * 64 + r];
        const float inv = 1.0f / lsum;
#pragma unroll
        for (int mt = 0; mt < 4; ++mt) {
            const int sl = (mt * 4 + quad) ^ lm;
            f32x4 o = acc_o[mt][s];
#pragma unroll
            for (int p = 0; p < 3; ++p)
                o += *(const f32x4*)(mbuf + p * 4096 + r * 64 + sl * 4);
            u16x4 pkv;
#pragma unroll
            for (int r2 = 0; r2 < 4; ++r2)
                pkv[r2] = f2bf(o[r2] * inv);
            *reinterpret_cast<u16x4*>(Ot + (size_t)(q0 + r) * 512 +
                                      hq + mt * 16 + quad * 4) = pkv;
        }
    }
}

// ---------------------------------------------------------------------------
extern "C" void kernel_launch(void* const* d_in, const int* in_sizes, int n_in,
                              void* d_out, int out_size, void* d_ws, size_t ws_size,
                              hipStream_t stream) {
    (void)in_sizes; (void)n_in; (void)out_size; (void)ws_size;
    const float* X   = (const float*)d_in[0];
    const float* qw  = (const float*)d_in[1];
    const float* qb  = (const float*)d_in[2];
    const float* kw  = (const float*)d_in[3];
    const float* kb  = (const float*)d_in[4];
    const float* vw  = (const float*)d_in[5];
    const float* vb  = (const float*)d_in[6];
    const float* pw  = (const float*)d_in[7];
    const float* pb  = (const float*)d_in[8];
    const float* lqw = (const float*)d_in[9];

    const size_t E = (size_t)4096 * 512;
    const size_t WE = (size_t)512 * 512;
    u16* Xt    = (u16*)d_ws;
    u16* Qt    = Xt + E;
    u16* Kt    = Qt + E;
    u16* Vimg  = Kt + E;          // 8 heads x 128 tiles x 2048 u16 = E
    u16* Wqkv  = Vimg + E;        // 1536 x 512 stacked
    u16* Wp    = Wqkv + 3 * WE;
    float* lqw2g = (float*)(Wp + WE);   // 4096 fp32, 16B-aligned
    u16* Ot    = Xt;              // reuse (dead after qkv)

    prep<<<dim3(64, 13), dim3(256), 0, stream>>>(X, Xt, qw, kw, vw, pw,
                                                 Wqkv, Wp, lqw, lqw2g);
    qkv_gemm<<<dim3(32, 12), dim3(512), 0, stream>>>(Wqkv, Xt, qb, kb, vb, Qt, Kt, Vimg);
    flash_attn<<<dim3(512), dim3(256), 0, stream>>>(Qt, Kt, Vimg, lqw2g, Ot);
    out_gemm<<<dim3(64, 4), dim3(256), 0, stream>>>(Wp, Ot, pb, (float*)d_out);
}